// Round 8
// baseline (297.035 us; speedup 1.0000x reference)
//
#include <hip/hip_runtime.h>
#include <math.h>

#define NNODES 50000
#define NEDGES 500000
#define HID 128
#define NCLS 40

using short8v = __attribute__((ext_vector_type(8))) short;
using float4v = __attribute__((ext_vector_type(4))) float;
using float2v = __attribute__((ext_vector_type(2))) float;

static __device__ __forceinline__ unsigned short f2bf(float f) {
    unsigned int u = __float_as_uint(f);
    u += 0x7FFFu + ((u >> 16) & 1u);   // RNE
    return (unsigned short)(u >> 16);
}
static __device__ __forceinline__ float bflo(unsigned int p) {
    return __uint_as_float(p << 16);
}
static __device__ __forceinline__ float bfhi(unsigned int p) {
    return __uint_as_float(p & 0xFFFF0000u);
}
static __device__ __forceinline__ float2v up2(unsigned int p) {
    float2v r = {bflo(p), bfhi(p)};
    return r;
}
#if __has_builtin(__builtin_elementwise_fma)
#define PKFMA(acc, vv, pp) (acc) = __builtin_elementwise_fma((vv), (pp), (acc))
#else
#define PKFMA(acc, vv, pp)                                                      \
    do { (acc).x = fmaf((vv).x, (pp).x, (acc).x);                               \
         (acc).y = fmaf((vv).y, (pp).y, (acc).y); } while (0)
#endif

// ---------------------------------------------------------------------------
// prep_edges: rowptrs for A/B + interleaved {col,val} streams
// ---------------------------------------------------------------------------
static __device__ __forceinline__ void rowptr_body(const int* __restrict__ row,
                                                   int e, int* __restrict__ rp) {
    if (e >= NEDGES) return;
    int r = row[e];
    int prev = (e == 0) ? -1 : row[e - 1];
    for (int q = prev + 1; q <= r; ++q) rp[q] = e;
    if (e == NEDGES - 1) {
        for (int q = r + 1; q <= NNODES; ++q) rp[q] = NEDGES;
    }
}

static __global__ void prep_edges_kernel(const int* __restrict__ arow,
                                         const int* __restrict__ acol,
                                         const float* __restrict__ aval,
                                         const int* __restrict__ brow,
                                         const int* __restrict__ bcol,
                                         const float* __restrict__ bval,
                                         const int* __restrict__ id,
                                         int* __restrict__ rpa, int* __restrict__ rpb,
                                         int2* __restrict__ cvA, int2* __restrict__ cvB,
                                         int gE) {
    int bid = blockIdx.x;
    if (bid < gE) {
        rowptr_body(arow, bid * 256 + threadIdx.x, rpa);
    } else if (bid < 2 * gE) {
        rowptr_body(brow, (bid - gE) * 256 + threadIdx.x, rpb);
    } else if (bid < 3 * gE) {
        int e = (bid - 2 * gE) * 256 + threadIdx.x;
        if (e < NEDGES) cvA[e] = make_int2(acol[e], __float_as_int(aval[e]));
    } else {
        int e = (bid - 3 * gE) * 256 + threadIdx.x;
        if (e < NEDGES) cvB[e] = make_int2(id[bcol[e]], __float_as_int(bval[e]));
    }
}

// ---------------------------------------------------------------------------
// prep_x: x0b = bf16(x0); xmb = bf16(r*x0 + (1-r)*x0[id])
// ---------------------------------------------------------------------------
static __global__ void prep_x_kernel(const float4* __restrict__ x, const int* __restrict__ id,
                                     const float* __restrict__ mixr,
                                     uint2* __restrict__ x0b, uint2* xmb) {
    int i = blockIdx.x * blockDim.x + threadIdx.x;   // exactly N*HID/4
    int n = i >> 5, qq = i & 31;
    float r = mixr[0];
    float4 a = x[i];
    float4 b = x[(size_t)id[n] * 32 + qq];
    uint2 pa, pm;
    pa.x = (unsigned)f2bf(a.x) | ((unsigned)f2bf(a.y) << 16);
    pa.y = (unsigned)f2bf(a.z) | ((unsigned)f2bf(a.w) << 16);
    pm.x = (unsigned)f2bf(r * a.x + (1.f - r) * b.x) |
           ((unsigned)f2bf(r * a.y + (1.f - r) * b.y) << 16);
    pm.y = (unsigned)f2bf(r * a.z + (1.f - r) * b.z) |
           ((unsigned)f2bf(r * a.w + (1.f - r) * b.w) << 16);
    x0b[i] = pa;
    xmb[i] = pm;
}

// ---------------------------------------------------------------------------
// prep_w: Wt[mat][n][k] for 6 mats (0-2 Wl, 3-5 Wr), then WoT[c][k] (48-pad)
// ---------------------------------------------------------------------------
static __global__ void prep_w_kernel(const float* __restrict__ Wl, const float* __restrict__ Wr,
                                     const float* __restrict__ Wout,
                                     unsigned short* __restrict__ Wt,
                                     unsigned short* __restrict__ WoT) {
    int t = blockIdx.x * blockDim.x + threadIdx.x;   // exactly 6*16384 + 48*128
    if (t < 6 * 16384) {
        int mat = t >> 14, idx = t & 16383;
        int n = idx >> 7, k = idx & 127;
        const float* src = (mat < 3) ? (Wl + mat * 16384) : (Wr + (mat - 3) * 16384);
        Wt[t] = f2bf(src[k * HID + n]);
    } else {
        int u = t - 6 * 16384;
        int c = u >> 7, k = u & 127;
        WoT[u] = (c < NCLS) ? f2bf(Wout[k * NCLS + c]) : (unsigned short)0;
    }
}

// ---------------------------------------------------------------------------
// spmm2: wave w<N -> S[w,:] via A edges; w>=N -> T via B edges.
// Quarter-wave (16 lanes x 16B) per row gather, unroll x2 -> 8 rows in flight.
// ---------------------------------------------------------------------------
static __global__ __launch_bounds__(256) void spmm2_kernel(
    const unsigned short* __restrict__ y,
    const int2* __restrict__ cvA, const int* __restrict__ rpA,
    unsigned short* __restrict__ SA,
    const int2* __restrict__ cvB, const int* __restrict__ rpB,
    unsigned short* __restrict__ SB) {
    int w = blockIdx.x * 4 + (threadIdx.x >> 6);
    const int l = threadIdx.x & 63;
    const int q = l >> 4, j = l & 15;
    const int2* cv; const int* rp; unsigned short* dst; int node;
    if (w < NNODES) { cv = cvA; rp = rpA; dst = SA; node = w; }
    else            { cv = cvB; rp = rpB; dst = SB; node = w - NNODES; }
    int e0 = rp[node], e1 = rp[node + 1];
    float2v a0 = {0.f, 0.f}, a1 = {0.f, 0.f}, a2 = {0.f, 0.f}, a3 = {0.f, 0.f};
    int e = e0 + q;
    for (; e + 4 < e1; e += 8) {
        int2 m0 = cv[e], m1 = cv[e + 4];
        uint4 p0 = *(const uint4*)(y + (size_t)m0.x * HID + j * 8);
        uint4 p1 = *(const uint4*)(y + (size_t)m1.x * HID + j * 8);
        float v0 = __int_as_float(m0.y), v1 = __int_as_float(m1.y);
        float2v vv0 = {v0, v0}, vv1 = {v1, v1};
        PKFMA(a0, vv0, up2(p0.x)); PKFMA(a1, vv0, up2(p0.y));
        PKFMA(a2, vv0, up2(p0.z)); PKFMA(a3, vv0, up2(p0.w));
        PKFMA(a0, vv1, up2(p1.x)); PKFMA(a1, vv1, up2(p1.y));
        PKFMA(a2, vv1, up2(p1.z)); PKFMA(a3, vv1, up2(p1.w));
    }
    if (e < e1) {
        int2 m0 = cv[e];
        uint4 p0 = *(const uint4*)(y + (size_t)m0.x * HID + j * 8);
        float v0 = __int_as_float(m0.y);
        float2v vv0 = {v0, v0};
        PKFMA(a0, vv0, up2(p0.x)); PKFMA(a1, vv0, up2(p0.y));
        PKFMA(a2, vv0, up2(p0.z)); PKFMA(a3, vv0, up2(p0.w));
    }
    a0.x += __shfl_xor(a0.x, 16); a0.y += __shfl_xor(a0.y, 16);
    a1.x += __shfl_xor(a1.x, 16); a1.y += __shfl_xor(a1.y, 16);
    a2.x += __shfl_xor(a2.x, 16); a2.y += __shfl_xor(a2.y, 16);
    a3.x += __shfl_xor(a3.x, 16); a3.y += __shfl_xor(a3.y, 16);
    a0.x += __shfl_xor(a0.x, 32); a0.y += __shfl_xor(a0.y, 32);
    a1.x += __shfl_xor(a1.x, 32); a1.y += __shfl_xor(a1.y, 32);
    a2.x += __shfl_xor(a2.x, 32); a2.y += __shfl_xor(a2.y, 32);
    a3.x += __shfl_xor(a3.x, 32); a3.y += __shfl_xor(a3.y, 32);
    if (l < 16) {
        uint4 o;
        o.x = (unsigned)f2bf(a0.x) | ((unsigned)f2bf(a0.y) << 16);
        o.y = (unsigned)f2bf(a1.x) | ((unsigned)f2bf(a1.y) << 16);
        o.z = (unsigned)f2bf(a2.x) | ((unsigned)f2bf(a2.y) << 16);
        o.w = (unsigned)f2bf(a3.x) | ((unsigned)f2bf(a3.y) << 16);
        *(uint4*)(dst + (size_t)node * HID + l * 8) = o;
    }
}

// ---------------------------------------------------------------------------
// MFMA helpers: swapped-operand layout (D[row=lane&15][col=tile*16+(lane>>4)*4+i])
// ---------------------------------------------------------------------------
#define LOAD_W4(ptr, w0, w1, w2, w3)                                            \
    w0 = *(const short8v*)(ptr);                                                \
    w1 = *(const short8v*)((ptr) + 32);                                         \
    w2 = *(const short8v*)((ptr) + 64);                                         \
    w3 = *(const short8v*)((ptr) + 96);

#define MFMA4(w0, w1, w2, w3, x0, x1, x2, x3, t)                                \
    t = __builtin_amdgcn_mfma_f32_16x16x32_bf16(w0, x0, t, 0, 0, 0);            \
    t = __builtin_amdgcn_mfma_f32_16x16x32_bf16(w1, x1, t, 0, 0, 0);            \
    t = __builtin_amdgcn_mfma_f32_16x16x32_bf16(w2, x2, t, 0, 0, 0);            \
    t = __builtin_amdgcn_mfma_f32_16x16x32_bf16(w3, x3, t, 0, 0, 0);

// gemm_y: y = A @ Wt^T. 256 threads = 4 waves, wave owns 2 col-tiles, 16 rows.
static __global__ __launch_bounds__(256, 4) void gemm_y_kernel(
    const unsigned short* __restrict__ A, const unsigned short* __restrict__ Wt,
    unsigned short* __restrict__ out) {
    const int lr = threadIdx.x & 15;
    const int lg = (threadIdx.x >> 4) & 3;
    const int wv = threadIdx.x >> 6;
    const int row = blockIdx.x * 16 + lr;
    const size_t rbase = (size_t)row * HID;
    const unsigned short* ap = A + rbase + lg * 8;
    short8v a0 = *(const short8v*)(ap);
    short8v a1 = *(const short8v*)(ap + 32);
    short8v a2 = *(const short8v*)(ap + 64);
    short8v a3 = *(const short8v*)(ap + 96);
#pragma unroll
    for (int c = 0; c < 2; ++c) {
        const int tile = wv * 2 + c;
        const unsigned short* wp = Wt + (size_t)(tile * 16 + lr) * HID + lg * 8;
        short8v w0, w1, w2, w3;
        LOAD_W4(wp, w0, w1, w2, w3)
        float4v t = {0.f, 0.f, 0.f, 0.f};
        MFMA4(w0, w1, w2, w3, a0, a1, a2, a3, t)
        uint2 o;
        o.x = (unsigned)f2bf(t[0]) | ((unsigned)f2bf(t[1]) << 16);
        o.y = (unsigned)f2bf(t[2]) | ((unsigned)f2bf(t[3]) << 16);
        *(uint2*)(out + rbase + tile * 16 + lg * 4) = o;
    }
}

// ---------------------------------------------------------------------------
// fused_layer<DO_HY>: 256 threads = 4 waves over 16 rows; wave owns 2 col-tiles
// of every pass. z = xm@Wr + b; DO_HY: hv = relu(S + Ah@Wr + b);
// xm' = r*relu(S+z) + (1-r)*relu(T+z).
// DO_HY:  store xm',h; h->LDS; barrier; y = h@WtLn (full-K frags from LDS).
// !DO_HY: xm'->LDS; barrier; waves 0-2: logits tiles -> LDS; LSE; store out.
// ---------------------------------------------------------------------------
template <bool DO_HY>
static __global__ __launch_bounds__(256, 4) void fused_layer_kernel(
    const unsigned short* __restrict__ Ah,
    const unsigned short* xmIn,
    const unsigned short* __restrict__ WtR,
    const unsigned short* __restrict__ WtLn,
    const unsigned short* __restrict__ S,
    const unsigned short* __restrict__ T,
    const float* __restrict__ bias,
    const float* __restrict__ mixr,
    unsigned short* __restrict__ hOut,
    unsigned short* __restrict__ yOut,
    unsigned short* xmOut,
    const unsigned short* __restrict__ WoT,
    const float* __restrict__ bout,
    float* __restrict__ out) {
    __shared__ __align__(16) unsigned short hs[16][136];
    __shared__ float lgt[16][52];
    __shared__ float lse_s[16];
    const int lr = threadIdx.x & 15;
    const int lg = (threadIdx.x >> 4) & 3;
    const int wv = threadIdx.x >> 6;
    const int row = blockIdx.x * 16 + lr;
    const size_t rbase = (size_t)row * HID;
    const float rr = mixr[0];

    // ---- prefetch S/T for this wave's 2 col-tiles
    uint2 sv[2], tv[2];
#pragma unroll
    for (int c = 0; c < 2; ++c) {
        const size_t g = rbase + (wv * 2 + c) * 16 + lg * 4;
        sv[c] = *(const uint2*)(S + g);
        tv[c] = *(const uint2*)(T + g);
    }

    // ---- A-operand (= X) fragments
    const unsigned short* xp = xmIn + rbase + lg * 8;
    short8v ax0 = *(const short8v*)(xp);
    short8v ax1 = *(const short8v*)(xp + 32);
    short8v ax2 = *(const short8v*)(xp + 64);
    short8v ax3 = *(const short8v*)(xp + 96);
    short8v ah0, ah1, ah2, ah3;
    if constexpr (DO_HY) {
        const unsigned short* hp = Ah + rbase + lg * 8;
        ah0 = *(const short8v*)(hp);
        ah1 = *(const short8v*)(hp + 32);
        ah2 = *(const short8v*)(hp + 64);
        ah3 = *(const short8v*)(hp + 96);
    }

    // ---- dual MFMA (z and h share W fragments), 2 tiles per wave
    float4v accz[2], acch[2];
#pragma unroll
    for (int c = 0; c < 2; ++c) {
        const int tile = wv * 2 + c;
        const unsigned short* wp = WtR + (size_t)(tile * 16 + lr) * HID + lg * 8;
        short8v w0, w1, w2, w3;
        LOAD_W4(wp, w0, w1, w2, w3)
        float4v t = {0.f, 0.f, 0.f, 0.f};
        MFMA4(w0, w1, w2, w3, ax0, ax1, ax2, ax3, t)
        accz[c] = t;
        if constexpr (DO_HY) {
            float4v u = {0.f, 0.f, 0.f, 0.f};
            MFMA4(w0, w1, w2, w3, ah0, ah1, ah2, ah3, u)
            acch[c] = u;
        }
    }

    // ---- epilogue for this wave's 2 col-tiles
#pragma unroll
    for (int c = 0; c < 2; ++c) {
        const int col0 = (wv * 2 + c) * 16 + lg * 4;
        const float4v bv = *(const float4v*)(bias + col0);
        const float s4[4] = {bflo(sv[c].x), bfhi(sv[c].x), bflo(sv[c].y), bfhi(sv[c].y)};
        const float t4[4] = {bflo(tv[c].x), bfhi(tv[c].x), bflo(tv[c].y), bfhi(tv[c].y)};
        unsigned short xm4[4], h4[4];
#pragma unroll
        for (int i = 0; i < 4; ++i) {
            const float z = accz[c][i] + bv[i];
            const float xa = fmaxf(s4[i] + z, 0.f);
            const float xb = fmaxf(t4[i] + z, 0.f);
            xm4[i] = f2bf(rr * xa + (1.f - rr) * xb);
            if constexpr (DO_HY) h4[i] = f2bf(fmaxf(acch[c][i] + s4[i] + bv[i], 0.f));
        }
        uint2 xmv;
        xmv.x = (unsigned)xm4[0] | ((unsigned)xm4[1] << 16);
        xmv.y = (unsigned)xm4[2] | ((unsigned)xm4[3] << 16);
        if constexpr (DO_HY) {
            uint2 hv;
            hv.x = (unsigned)h4[0] | ((unsigned)h4[1] << 16);
            hv.y = (unsigned)h4[2] | ((unsigned)h4[3] << 16);
            *(uint2*)(xmOut + rbase + col0) = xmv;
            *(uint2*)(hOut + rbase + col0) = hv;
            *(uint2*)(&hs[lr][col0]) = hv;
        } else {
            *(uint2*)(&hs[lr][col0]) = xmv;
        }
    }
    __syncthreads();

    // ---- stage 2: full-K A-frags from the LDS tile
    const unsigned short* lp = &hs[lr][lg * 8];
    short8v c0 = *(const short8v*)(lp);
    short8v c1 = *(const short8v*)(lp + 32);
    short8v c2 = *(const short8v*)(lp + 64);
    short8v c3 = *(const short8v*)(lp + 96);

    if constexpr (DO_HY) {
        // y = h @ WtLn, 2 tiles per wave
#pragma unroll
        for (int c = 0; c < 2; ++c) {
            const int tile = wv * 2 + c;
            const unsigned short* wq = WtLn + (size_t)(tile * 16 + lr) * HID + lg * 8;
            short8v w0, w1, w2, w3;
            LOAD_W4(wq, w0, w1, w2, w3)
            float4v t = {0.f, 0.f, 0.f, 0.f};
            MFMA4(w0, w1, w2, w3, c0, c1, c2, c3, t)
            uint2 o;
            o.x = (unsigned)f2bf(t[0]) | ((unsigned)f2bf(t[1]) << 16);
            o.y = (unsigned)f2bf(t[2]) | ((unsigned)f2bf(t[3]) << 16);
            *(uint2*)(yOut + rbase + tile * 16 + lg * 4) = o;
        }
    } else {
        // head: waves 0-2 compute one 16-col logits tile each (cols 0..47)
        if (wv < 3) {
            const unsigned short* wq = WoT + (size_t)(wv * 16 + lr) * HID + lg * 8;
            short8v w0, w1, w2, w3;
            LOAD_W4(wq, w0, w1, w2, w3)
            float4v t = {0.f, 0.f, 0.f, 0.f};
            MFMA4(w0, w1, w2, w3, c0, c1, c2, c3, t)
            const int col0 = wv * 16 + lg * 4;
            if (col0 < NCLS) {
#pragma unroll
                for (int i = 0; i < 4; ++i)
                    lgt[lr][col0 + i] = t[i] + bout[col0 + i];
            }
        }
        __syncthreads();
        if (threadIdx.x < 16) {
            const int r = threadIdx.x;
            float mx = -INFINITY;
#pragma unroll 4
            for (int j = 0; j < NCLS; ++j) mx = fmaxf(mx, lgt[r][j]);
            float s = 0.f;
#pragma unroll 4
            for (int j = 0; j < NCLS; ++j) s += expf(lgt[r][j] - mx);
            lse_s[r] = mx + logf(s);
        }
        __syncthreads();
        const int gr0 = blockIdx.x * 16;
        for (int idx = threadIdx.x; idx < 16 * NCLS; idx += 256) {
            const int r = idx / NCLS;
            const int cc = idx - r * NCLS;
            out[(size_t)(gr0 + r) * NCLS + cc] = lgt[r][cc] - lse_s[r];
        }
    }
}

// ---------------------------------------------------------------------------
extern "C" void kernel_launch(void* const* d_in, const int* in_sizes, int n_in,
                              void* d_out, int out_size, void* d_ws, size_t ws_size,
                              hipStream_t stream) {
    const float* x0   = (const float*)d_in[0];
    const int*   arow = (const int*)d_in[1];
    const int*   acol = (const int*)d_in[2];
    const float* aval = (const float*)d_in[3];
    const int*   brow = (const int*)d_in[4];
    const int*   bcol = (const int*)d_in[5];
    const float* bval = (const float*)d_in[6];
    const float* mixr = (const float*)d_in[7];
    const int*   id   = (const int*)d_in[8];
    const float* Wl   = (const float*)d_in[9];
    const float* Wr   = (const float*)d_in[10];
    const float* bs   = (const float*)d_in[11];
    const float* Wout = (const float*)d_in[12];
    const float* bout = (const float*)d_in[13];
    float* out = (float*)d_out;

    const size_t NF = (size_t)NNODES * HID;   // 6.4M
    unsigned short* x0b = (unsigned short*)d_ws;
    unsigned short* xmb = x0b + NF;
    unsigned short* h1b = xmb + NF;
    unsigned short* h2b = h1b + NF;
    unsigned short* yb  = h2b + NF;
    unsigned short* S   = yb + NF;
    unsigned short* T   = S + NF;
    unsigned short* Wt  = T + NF;             // 6 * 16384 bf16
    unsigned short* WoT = Wt + 6 * 16384;     // 48 * 128 bf16
    int2* cvA = (int2*)(WoT + 48 * 128);      // E int2
    int2* cvB = cvA + NEDGES;
    int* rpa = (int*)(cvB + NEDGES);
    int* rpb = rpa + (NNODES + 1);

    const int gE = (NEDGES + 255) / 256;      // 1954
    const int gC = NNODES * HID / 4 / 256;    // 6250
    const int gG = NNODES / 16;               // 3125 (exact)
    const int gS2 = 2 * NNODES * 64 / 256;    // 25000

    prep_edges_kernel<<<4 * gE, 256, 0, stream>>>(arow, acol, aval, brow, bcol, bval,
                                                  id, rpa, rpb, cvA, cvB, gE);
    prep_x_kernel<<<gC, 256, 0, stream>>>((const float4*)x0, id, mixr, (uint2*)x0b, (uint2*)xmb);
    prep_w_kernel<<<(6 * 16384 + 48 * 128) / 256, 256, 0, stream>>>(Wl, Wr, Wout, Wt, WoT);

    // y0 = x0 @ Wl0
    gemm_y_kernel<<<gG, 256, 0, stream>>>(x0b, Wt + 0 * 16384, yb);

    // ---- layer 0
    spmm2_kernel<<<gS2, 256, 0, stream>>>(yb, cvA, rpa, S, cvB, rpb, T);
    fused_layer_kernel<true><<<gG, 256, 0, stream>>>(
        x0b, xmb, Wt + 3 * 16384, Wt + 1 * 16384, S, T, bs, mixr,
        h1b, yb, xmb, nullptr, nullptr, nullptr);

    // ---- layer 1
    spmm2_kernel<<<gS2, 256, 0, stream>>>(yb, cvA, rpa, S, cvB, rpb, T);
    fused_layer_kernel<true><<<gG, 256, 0, stream>>>(
        h1b, xmb, Wt + 4 * 16384, Wt + 2 * 16384, S, T, bs + 128, mixr,
        h2b, yb, xmb, nullptr, nullptr, nullptr);

    // ---- layer 2 (+ head)
    spmm2_kernel<<<gS2, 256, 0, stream>>>(yb, cvA, rpa, S, cvB, rpb, T);
    fused_layer_kernel<false><<<gG, 256, 0, stream>>>(
        h2b, xmb, Wt + 5 * 16384, nullptr, S, T, bs + 256, mixr,
        nullptr, nullptr, nullptr, WoT, bout, out);
}

// Round 9
// 270.994 us; speedup vs baseline: 1.0961x; 1.0961x over previous
//
#include <hip/hip_runtime.h>
#include <hip/hip_fp16.h>
#include <math.h>

#define NNODES 50000
#define NEDGES 500000
#define HID 128
#define NCLS 40

using short8v = __attribute__((ext_vector_type(8))) short;
using float4v = __attribute__((ext_vector_type(4))) float;

static __device__ __forceinline__ unsigned short f2bf(float f) {
    unsigned int u = __float_as_uint(f);
    u += 0x7FFFu + ((u >> 16) & 1u);   // RNE
    return (unsigned short)(u >> 16);
}
static __device__ __forceinline__ float bflo(unsigned int p) {
    return __uint_as_float(p << 16);
}
static __device__ __forceinline__ float bfhi(unsigned int p) {
    return __uint_as_float(p & 0xFFFF0000u);
}
static __device__ __forceinline__ unsigned h2u(__half2 h) {
    union { __half2 h; unsigned u; } x; x.h = h; return x.u;
}
static __device__ __forceinline__ __half2 u2h(unsigned u) {
    union { unsigned u; __half2 h; } x; x.u = u; return x.h;
}

// ---------------------------------------------------------------------------
// prep_edges: rowptrs for A/B + interleaved {col, val-as-half2} streams
// ---------------------------------------------------------------------------
static __device__ __forceinline__ void rowptr_body(const int* __restrict__ row,
                                                   int e, int* __restrict__ rp) {
    if (e >= NEDGES) return;
    int r = row[e];
    int prev = (e == 0) ? -1 : row[e - 1];
    for (int q = prev + 1; q <= r; ++q) rp[q] = e;
    if (e == NEDGES - 1) {
        for (int q = r + 1; q <= NNODES; ++q) rp[q] = NEDGES;
    }
}

static __global__ void prep_edges_kernel(const int* __restrict__ arow,
                                         const int* __restrict__ acol,
                                         const float* __restrict__ aval,
                                         const int* __restrict__ brow,
                                         const int* __restrict__ bcol,
                                         const float* __restrict__ bval,
                                         const int* __restrict__ id,
                                         int* __restrict__ rpa, int* __restrict__ rpb,
                                         int2* __restrict__ cvA, int2* __restrict__ cvB,
                                         int gE) {
    int bid = blockIdx.x;
    if (bid < gE) {
        rowptr_body(arow, bid * 256 + threadIdx.x, rpa);
    } else if (bid < 2 * gE) {
        rowptr_body(brow, (bid - gE) * 256 + threadIdx.x, rpb);
    } else if (bid < 3 * gE) {
        int e = (bid - 2 * gE) * 256 + threadIdx.x;
        if (e < NEDGES) {
            __half2 v = __float2half2_rn(aval[e]);
            cvA[e] = make_int2(acol[e], (int)h2u(v));
        }
    } else {
        int e = (bid - 3 * gE) * 256 + threadIdx.x;
        if (e < NEDGES) {
            __half2 v = __float2half2_rn(bval[e]);
            cvB[e] = make_int2(id[bcol[e]], (int)h2u(v));
        }
    }
}

// ---------------------------------------------------------------------------
// prep_x: x0b = bf16(x0); xmb = bf16(r*x0 + (1-r)*x0[id])
// ---------------------------------------------------------------------------
static __global__ void prep_x_kernel(const float4* __restrict__ x, const int* __restrict__ id,
                                     const float* __restrict__ mixr,
                                     uint2* __restrict__ x0b, uint2* xmb) {
    int i = blockIdx.x * blockDim.x + threadIdx.x;   // exactly N*HID/4
    int n = i >> 5, qq = i & 31;
    float r = mixr[0];
    float4 a = x[i];
    float4 b = x[(size_t)id[n] * 32 + qq];
    uint2 pa, pm;
    pa.x = (unsigned)f2bf(a.x) | ((unsigned)f2bf(a.y) << 16);
    pa.y = (unsigned)f2bf(a.z) | ((unsigned)f2bf(a.w) << 16);
    pm.x = (unsigned)f2bf(r * a.x + (1.f - r) * b.x) |
           ((unsigned)f2bf(r * a.y + (1.f - r) * b.y) << 16);
    pm.y = (unsigned)f2bf(r * a.z + (1.f - r) * b.z) |
           ((unsigned)f2bf(r * a.w + (1.f - r) * b.w) << 16);
    x0b[i] = pa;
    xmb[i] = pm;
}

// ---------------------------------------------------------------------------
// prep_w: Wt[mat][n][k] for 6 mats (0-2 Wl, 3-5 Wr), then WoT[c][k] (48-pad)
// ---------------------------------------------------------------------------
static __global__ void prep_w_kernel(const float* __restrict__ Wl, const float* __restrict__ Wr,
                                     const float* __restrict__ Wout,
                                     unsigned short* __restrict__ Wt,
                                     unsigned short* __restrict__ WoT) {
    int t = blockIdx.x * blockDim.x + threadIdx.x;   // exactly 6*16384 + 48*128
    if (t < 6 * 16384) {
        int mat = t >> 14, idx = t & 16383;
        int n = idx >> 7, k = idx & 127;
        const float* src = (mat < 3) ? (Wl + mat * 16384) : (Wr + (mat - 3) * 16384);
        Wt[t] = f2bf(src[k * HID + n]);
    } else {
        int u = t - 6 * 16384;
        int c = u >> 7, k = u & 127;
        WoT[u] = (c < NCLS) ? f2bf(Wout[k * NCLS + c]) : (unsigned short)0;
    }
}

// ---------------------------------------------------------------------------
// spmm2: wave w<N -> S[w,:] via A edges; w>=N -> T via B edges. y/S/T are f16.
// Quarter-wave (16 lanes x 16B) per row gather; 2 edges/iter; cv prefetched
// one iteration ahead (breaks cv->gather serial chain); __hfma2 accumulate.
// ---------------------------------------------------------------------------
static __global__ __launch_bounds__(256) void spmm2_kernel(
    const __half* __restrict__ y,
    const int2* __restrict__ cvA, const int* __restrict__ rpA,
    __half* __restrict__ SA,
    const int2* __restrict__ cvB, const int* __restrict__ rpB,
    __half* __restrict__ SB) {
    int w = blockIdx.x * 4 + (threadIdx.x >> 6);
    const int l = threadIdx.x & 63;
    const int q = l >> 4, j = l & 15;
    const int2* cv; const int* rp; __half* dst; int node;
    if (w < NNODES) { cv = cvA; rp = rpA; dst = SA; node = w; }
    else            { cv = cvB; rp = rpB; dst = SB; node = w - NNODES; }
    const int e0 = rp[node], e1 = rp[node + 1];
    __half2 a0 = __float2half2_rn(0.f), a1 = a0, a2 = a0, a3 = a0;
    int e = e0 + q;
    int2 m0, m1;
    bool have = (e + 4 < e1);
    if (have) { m0 = cv[e]; m1 = cv[e + 4]; }
    while (have) {
        const int e2 = e + 8;
        const bool nxt = (e2 + 4 < e1);
        int2 k0 = m0, k1 = m1;
        if (nxt) { k0 = cv[e2]; k1 = cv[e2 + 4]; }
        const uint4 p0 = *(const uint4*)(y + (size_t)m0.x * HID + j * 8);
        const uint4 p1 = *(const uint4*)(y + (size_t)m1.x * HID + j * 8);
        const __half2 v0 = u2h((unsigned)m0.y), v1 = u2h((unsigned)m1.y);
        a0 = __hfma2(u2h(p0.x), v0, a0); a1 = __hfma2(u2h(p0.y), v0, a1);
        a2 = __hfma2(u2h(p0.z), v0, a2); a3 = __hfma2(u2h(p0.w), v0, a3);
        a0 = __hfma2(u2h(p1.x), v1, a0); a1 = __hfma2(u2h(p1.y), v1, a1);
        a2 = __hfma2(u2h(p1.z), v1, a2); a3 = __hfma2(u2h(p1.w), v1, a3);
        m0 = k0; m1 = k1; e = e2; have = nxt;
    }
    if (e < e1) {
        const int2 m = cv[e];
        const uint4 p = *(const uint4*)(y + (size_t)m.x * HID + j * 8);
        const __half2 v = u2h((unsigned)m.y);
        a0 = __hfma2(u2h(p.x), v, a0); a1 = __hfma2(u2h(p.y), v, a1);
        a2 = __hfma2(u2h(p.z), v, a2); a3 = __hfma2(u2h(p.w), v, a3);
    }
    a0 = __hadd2(a0, u2h(__shfl_xor((int)h2u(a0), 16)));
    a1 = __hadd2(a1, u2h(__shfl_xor((int)h2u(a1), 16)));
    a2 = __hadd2(a2, u2h(__shfl_xor((int)h2u(a2), 16)));
    a3 = __hadd2(a3, u2h(__shfl_xor((int)h2u(a3), 16)));
    a0 = __hadd2(a0, u2h(__shfl_xor((int)h2u(a0), 32)));
    a1 = __hadd2(a1, u2h(__shfl_xor((int)h2u(a1), 32)));
    a2 = __hadd2(a2, u2h(__shfl_xor((int)h2u(a2), 32)));
    a3 = __hadd2(a3, u2h(__shfl_xor((int)h2u(a3), 32)));
    if (l < 16) {
        uint4 o;
        o.x = h2u(a0); o.y = h2u(a1); o.z = h2u(a2); o.w = h2u(a3);
        *(uint4*)(dst + (size_t)node * HID + l * 8) = o;
    }
}

// ---------------------------------------------------------------------------
// MFMA helpers: swapped-operand layout (D[row=lane&15][col=tile*16+(lane>>4)*4+i])
// ---------------------------------------------------------------------------
#define LOAD_W4(ptr, w0, w1, w2, w3)                                            \
    w0 = *(const short8v*)(ptr);                                                \
    w1 = *(const short8v*)((ptr) + 32);                                         \
    w2 = *(const short8v*)((ptr) + 64);                                         \
    w3 = *(const short8v*)((ptr) + 96);

#define MFMA4(w0, w1, w2, w3, x0, x1, x2, x3, t)                                \
    t = __builtin_amdgcn_mfma_f32_16x16x32_bf16(w0, x0, t, 0, 0, 0);            \
    t = __builtin_amdgcn_mfma_f32_16x16x32_bf16(w1, x1, t, 0, 0, 0);            \
    t = __builtin_amdgcn_mfma_f32_16x16x32_bf16(w2, x2, t, 0, 0, 0);            \
    t = __builtin_amdgcn_mfma_f32_16x16x32_bf16(w3, x3, t, 0, 0, 0);

// gemm_y: y = A @ Wt^T (f16 out). Front-loaded A + 4 W tiles, refill by 4.
static __global__ __launch_bounds__(64, 2) void gemm_y_kernel(
    const unsigned short* __restrict__ A, const unsigned short* __restrict__ Wt,
    __half* __restrict__ out) {
    const int lr = threadIdx.x & 15;
    const int lg = threadIdx.x >> 4;
    const int row = blockIdx.x * 16 + lr;
    const size_t rbase = (size_t)row * HID;
    const unsigned short* ap = A + rbase + lg * 8;
    short8v a0 = *(const short8v*)(ap);
    short8v a1 = *(const short8v*)(ap + 32);
    short8v a2 = *(const short8v*)(ap + 64);
    short8v a3 = *(const short8v*)(ap + 96);
    const unsigned short* wb = Wt + (size_t)lr * HID + lg * 8;
    short8v q0[4], q1[4], q2[4], q3[4];
    LOAD_W4(wb + 0 * 2048, q0[0], q0[1], q0[2], q0[3])
    LOAD_W4(wb + 1 * 2048, q1[0], q1[1], q1[2], q1[3])
    LOAD_W4(wb + 2 * 2048, q2[0], q2[1], q2[2], q2[3])
    LOAD_W4(wb + 3 * 2048, q3[0], q3[1], q3[2], q3[3])
    __builtin_amdgcn_sched_barrier(0);
#define GY_TILE(c, W, refill)                                                   \
    {                                                                           \
        float4v t = {0.f, 0.f, 0.f, 0.f};                                       \
        MFMA4(W[0], W[1], W[2], W[3], a0, a1, a2, a3, t)                        \
        __half2 p01 = __floats2half2_rn(t[0], t[1]);                            \
        __half2 p23 = __floats2half2_rn(t[2], t[3]);                            \
        uint2 o; o.x = h2u(p01); o.y = h2u(p23);                                \
        *(uint2*)(out + rbase + (c) * 16 + lg * 4) = o;                         \
        if ((refill) >= 0) {                                                    \
            LOAD_W4(wb + (size_t)(refill) * 2048, W[0], W[1], W[2], W[3])       \
        }                                                                       \
    }
    GY_TILE(0, q0, 4) GY_TILE(1, q1, 5) GY_TILE(2, q2, 6) GY_TILE(3, q3, 7)
    GY_TILE(4, q0, -1) GY_TILE(5, q1, -1) GY_TILE(6, q2, -1) GY_TILE(7, q3, -1)
#undef GY_TILE
}

// ---------------------------------------------------------------------------
// fused_layer<DO_HY>: one wave per 16 rows. ALL global reads issued up front
// (S,T f16; xm,Ah bf16 frags; 4 W tiles) and pinned with sched_barrier(0) so
// ~40 loads are in flight through one latency window.
//   z = xm@Wr + b;  DO_HY: hv = relu(S + Ah@Wr + b)
//   xm' = r*relu(S+z) + (1-r)*relu(T+z)
//   DO_HY:  store xm',h; h->LDS; y = h@WtLn -> f16
//   !DO_HY: xm'->LDS; head: logits = xm'@WoT + bout; log_softmax -> out
// ---------------------------------------------------------------------------
template <bool DO_HY>
static __global__ __launch_bounds__(64, 2) void fused_layer_kernel(
    const unsigned short* __restrict__ Ah,
    const unsigned short* xmIn,
    const unsigned short* __restrict__ WtR,
    const unsigned short* __restrict__ WtLn,
    const __half* __restrict__ S,
    const __half* __restrict__ T,
    const float* __restrict__ bias,
    const float* __restrict__ mixr,
    unsigned short* __restrict__ hOut,
    __half* __restrict__ yOut,
    unsigned short* xmOut,
    const unsigned short* __restrict__ WoT,
    const float* __restrict__ bout,
    float* __restrict__ out) {
    __shared__ __align__(16) unsigned short hs[16][136];
    const int lr = threadIdx.x & 15;
    const int lg = threadIdx.x >> 4;
    const int row = blockIdx.x * 16 + lr;
    const size_t rbase = (size_t)row * HID;

    // ================= front load block (all independent) =================
    uint2 sv[8], tv[8];
#pragma unroll
    for (int c = 0; c < 8; ++c) {
        const size_t g = rbase + c * 16 + lg * 4;
        sv[c] = *(const uint2*)(S + g);
        tv[c] = *(const uint2*)(T + g);
    }
    const unsigned short* xp = xmIn + rbase + lg * 8;
    short8v ax0 = *(const short8v*)(xp);
    short8v ax1 = *(const short8v*)(xp + 32);
    short8v ax2 = *(const short8v*)(xp + 64);
    short8v ax3 = *(const short8v*)(xp + 96);
    short8v ah0, ah1, ah2, ah3;
    if constexpr (DO_HY) {
        const unsigned short* hp = Ah + rbase + lg * 8;
        ah0 = *(const short8v*)(hp);
        ah1 = *(const short8v*)(hp + 32);
        ah2 = *(const short8v*)(hp + 64);
        ah3 = *(const short8v*)(hp + 96);
    }
    const unsigned short* wb = WtR + (size_t)lr * HID + lg * 8;
    short8v q0[4], q1[4], q2[4], q3[4];
    LOAD_W4(wb + 0 * 2048, q0[0], q0[1], q0[2], q0[3])
    LOAD_W4(wb + 1 * 2048, q1[0], q1[1], q1[2], q1[3])
    LOAD_W4(wb + 2 * 2048, q2[0], q2[1], q2[2], q2[3])
    LOAD_W4(wb + 3 * 2048, q3[0], q3[1], q3[2], q3[3])
    const float rr = mixr[0];
    __builtin_amdgcn_sched_barrier(0);

    // ================= z (+h) MFMA passes, refill W by 4 =================
    float4v accz[8], acch[8];
#define ZH_TILE(c, W, refill)                                                   \
    {                                                                           \
        float4v t = {0.f, 0.f, 0.f, 0.f};                                       \
        MFMA4(W[0], W[1], W[2], W[3], ax0, ax1, ax2, ax3, t)                    \
        accz[c] = t;                                                            \
        if constexpr (DO_HY) {                                                  \
            float4v u = {0.f, 0.f, 0.f, 0.f};                                   \
            MFMA4(W[0], W[1], W[2], W[3], ah0, ah1, ah2, ah3, u)                \
            acch[c] = u;                                                        \
        }                                                                       \
        if ((refill) >= 0) {                                                    \
            LOAD_W4(wb + (size_t)(refill) * 2048, W[0], W[1], W[2], W[3])       \
        }                                                                       \
    }
    ZH_TILE(0, q0, 4) ZH_TILE(1, q1, 5) ZH_TILE(2, q2, 6) ZH_TILE(3, q3, 7)
    ZH_TILE(4, q0, -1) ZH_TILE(5, q1, -1) ZH_TILE(6, q2, -1) ZH_TILE(7, q3, -1)
#undef ZH_TILE

    // ================= epilogue (registers only) =================
#pragma unroll
    for (int c = 0; c < 8; ++c) {
        const int col0 = c * 16 + lg * 4;
        const float4v bv = *(const float4v*)(bias + col0);
        const float2 s01 = __half22float2(u2h(sv[c].x));
        const float2 s23 = __half22float2(u2h(sv[c].y));
        const float2 t01 = __half22float2(u2h(tv[c].x));
        const float2 t23 = __half22float2(u2h(tv[c].y));
        const float s4[4] = {s01.x, s01.y, s23.x, s23.y};
        const float t4[4] = {t01.x, t01.y, t23.x, t23.y};
        unsigned short xm4[4], h4[4];
#pragma unroll
        for (int i = 0; i < 4; ++i) {
            const float z = accz[c][i] + bv[i];
            const float xa = fmaxf(s4[i] + z, 0.f);
            const float xb = fmaxf(t4[i] + z, 0.f);
            xm4[i] = f2bf(rr * xa + (1.f - rr) * xb);
            if constexpr (DO_HY) h4[i] = f2bf(fmaxf(acch[c][i] + s4[i] + bv[i], 0.f));
        }
        uint2 xmv;
        xmv.x = (unsigned)xm4[0] | ((unsigned)xm4[1] << 16);
        xmv.y = (unsigned)xm4[2] | ((unsigned)xm4[3] << 16);
        if constexpr (DO_HY) {
            uint2 hv;
            hv.x = (unsigned)h4[0] | ((unsigned)h4[1] << 16);
            hv.y = (unsigned)h4[2] | ((unsigned)h4[3] << 16);
            *(uint2*)(xmOut + rbase + col0) = xmv;
            *(uint2*)(hOut + rbase + col0) = hv;
            *(uint2*)(&hs[lr][col0]) = hv;
        } else {
            *(uint2*)(&hs[lr][col0]) = xmv;
        }
    }

    if constexpr (DO_HY) {
        // preload WtLn tiles 0..3 before the barrier (lands during the wait)
        const unsigned short* wy = WtLn + (size_t)lr * HID + lg * 8;
        LOAD_W4(wy + 0 * 2048, q0[0], q0[1], q0[2], q0[3])
        LOAD_W4(wy + 1 * 2048, q1[0], q1[1], q1[2], q1[3])
        LOAD_W4(wy + 2 * 2048, q2[0], q2[1], q2[2], q2[3])
        LOAD_W4(wy + 3 * 2048, q3[0], q3[1], q3[2], q3[3])
        __syncthreads();
        const unsigned short* lp = &hs[lr][lg * 8];
        short8v c0 = *(const short8v*)(lp);
        short8v c1 = *(const short8v*)(lp + 32);
        short8v c2 = *(const short8v*)(lp + 64);
        short8v c3 = *(const short8v*)(lp + 96);
#define Y_TILE(c, W, refill)                                                    \
    {                                                                           \
        float4v t = {0.f, 0.f, 0.f, 0.f};                                       \
        MFMA4(W[0], W[1], W[2], W[3], c0, c1, c2, c3, t)                        \
        __half2 p01 = __floats2half2_rn(t[0], t[1]);                            \
        __half2 p23 = __floats2half2_rn(t[2], t[3]);                            \
        uint2 o; o.x = h2u(p01); o.y = h2u(p23);                                \
        *(uint2*)(yOut + rbase + (c) * 16 + lg * 4) = o;                        \
        if ((refill) >= 0) {                                                    \
            LOAD_W4(wy + (size_t)(refill) * 2048, W[0], W[1], W[2], W[3])       \
        }                                                                       \
    }
        Y_TILE(0, q0, 4) Y_TILE(1, q1, 5) Y_TILE(2, q2, 6) Y_TILE(3, q3, 7)
        Y_TILE(4, q0, -1) Y_TILE(5, q1, -1) Y_TILE(6, q2, -1) Y_TILE(7, q3, -1)
#undef Y_TILE
    } else {
        __syncthreads();
        const unsigned short* lp = &hs[lr][lg * 8];
        short8v c0 = *(const short8v*)(lp);
        short8v c1 = *(const short8v*)(lp + 32);
        short8v c2 = *(const short8v*)(lp + 64);
        short8v c3 = *(const short8v*)(lp + 96);
        float lv[3][4];
        float mx = -INFINITY;
#pragma unroll
        for (int c = 0; c < 3; ++c) {
            const unsigned short* wq = WoT + (size_t)(c * 16 + lr) * HID + lg * 8;
            short8v w0, w1, w2, w3;
            LOAD_W4(wq, w0, w1, w2, w3)
            float4v t = {0.f, 0.f, 0.f, 0.f};
            MFMA4(w0, w1, w2, w3, c0, c1, c2, c3, t)
            const int col0 = c * 16 + lg * 4;
            const bool valid = col0 < NCLS;
#pragma unroll
            for (int i = 0; i < 4; ++i) {
                const float l = valid ? (t[i] + bout[col0 + i]) : -INFINITY;
                lv[c][i] = l;
                mx = fmaxf(mx, l);
            }
        }
        mx = fmaxf(mx, __shfl_xor(mx, 16));
        mx = fmaxf(mx, __shfl_xor(mx, 32));
        float sum = 0.f;
#pragma unroll
        for (int c = 0; c < 3; ++c)
#pragma unroll
            for (int i = 0; i < 4; ++i)
                if (lv[c][i] > -INFINITY) sum += expf(lv[c][i] - mx);
        sum += __shfl_xor(sum, 16);
        sum += __shfl_xor(sum, 32);
        const float lse = mx + logf(sum);
#pragma unroll
        for (int c = 0; c < 3; ++c) {
            const int col0 = c * 16 + lg * 4;
            if (col0 < NCLS) {
                float4 o = make_float4(lv[c][0] - lse, lv[c][1] - lse,
                                       lv[c][2] - lse, lv[c][3] - lse);
                *(float4*)(out + (size_t)row * NCLS + col0) = o;
            }
        }
    }
}

// ---------------------------------------------------------------------------
extern "C" void kernel_launch(void* const* d_in, const int* in_sizes, int n_in,
                              void* d_out, int out_size, void* d_ws, size_t ws_size,
                              hipStream_t stream) {
    const float* x0   = (const float*)d_in[0];
    const int*   arow = (const int*)d_in[1];
    const int*   acol = (const int*)d_in[2];
    const float* aval = (const float*)d_in[3];
    const int*   brow = (const int*)d_in[4];
    const int*   bcol = (const int*)d_in[5];
    const float* bval = (const float*)d_in[6];
    const float* mixr = (const float*)d_in[7];
    const int*   id   = (const int*)d_in[8];
    const float* Wl   = (const float*)d_in[9];
    const float* Wr   = (const float*)d_in[10];
    const float* bs   = (const float*)d_in[11];
    const float* Wout = (const float*)d_in[12];
    const float* bout = (const float*)d_in[13];
    float* out = (float*)d_out;

    const size_t NF = (size_t)NNODES * HID;   // 6.4M
    unsigned short* x0b = (unsigned short*)d_ws;
    unsigned short* xmb = x0b + NF;
    unsigned short* h1b = xmb + NF;
    unsigned short* h2b = h1b + NF;
    __half* yb = (__half*)(h2b + NF);
    __half* S  = yb + NF;
    __half* T  = S + NF;
    unsigned short* Wt  = (unsigned short*)(T + NF);   // 6 * 16384 bf16
    unsigned short* WoT = Wt + 6 * 16384;              // 48 * 128 bf16
    int2* cvA = (int2*)(WoT + 48 * 128);               // E int2
    int2* cvB = cvA + NEDGES;
    int* rpa = (int*)(cvB + NEDGES);
    int* rpb = rpa + (NNODES + 1);

    const int gE = (NEDGES + 255) / 256;      // 1954
    const int gC = NNODES * HID / 4 / 256;    // 6250
    const int gG = NNODES / 16;               // 3125 (exact)
    const int gS2 = 2 * NNODES * 64 / 256;    // 25000

    prep_edges_kernel<<<4 * gE, 256, 0, stream>>>(arow, acol, aval, brow, bcol, bval,
                                                  id, rpa, rpb, cvA, cvB, gE);
    prep_x_kernel<<<gC, 256, 0, stream>>>((const float4*)x0, id, mixr, (uint2*)x0b, (uint2*)xmb);
    prep_w_kernel<<<(6 * 16384 + 48 * 128) / 256, 256, 0, stream>>>(Wl, Wr, Wout, Wt, WoT);

    // y0 = x0 @ Wl0
    gemm_y_kernel<<<gG, 64, 0, stream>>>(x0b, Wt + 0 * 16384, yb);

    // ---- layer 0
    spmm2_kernel<<<gS2, 256, 0, stream>>>(yb, cvA, rpa, S, cvB, rpb, T);
    fused_layer_kernel<true><<<gG, 64, 0, stream>>>(
        x0b, xmb, Wt + 3 * 16384, Wt + 1 * 16384, S, T, bs, mixr,
        h1b, yb, xmb, nullptr, nullptr, nullptr);

    // ---- layer 1
    spmm2_kernel<<<gS2, 256, 0, stream>>>(yb, cvA, rpa, S, cvB, rpb, T);
    fused_layer_kernel<true><<<gG, 64, 0, stream>>>(
        h1b, xmb, Wt + 4 * 16384, Wt + 2 * 16384, S, T, bs + 128, mixr,
        h2b, yb, xmb, nullptr, nullptr, nullptr);

    // ---- layer 2 (+ head)
    spmm2_kernel<<<gS2, 256, 0, stream>>>(yb, cvA, rpa, S, cvB, rpb, T);
    fused_layer_kernel<false><<<gG, 64, 0, stream>>>(
        h2b, xmb, Wt + 5 * 16384, nullptr, S, T, bs + 256, mixr,
        nullptr, nullptr, nullptr, WoT, bout, out);
}